// Round 4
// baseline (303.202 us; speedup 1.0000x reference)
//
#include <hip/hip_runtime.h>

typedef __bf16 bf16x8 __attribute__((ext_vector_type(8)));
typedef float f32x4 __attribute__((ext_vector_type(4)));

#define MFMA_BF16 __builtin_amdgcn_mfma_f32_16x16x32_bf16

static constexpr int T_ = 2048;
static constexpr int C_ = 1024;
static constexpr int H_ = 16;
static constexpr int KVH_ = 4;
static constexpr int D_ = 64;
static constexpr float SCALE_ = 0.125f;   // 1/sqrt(64)
static constexpr float NEG_BIG = -1.0e30f;

// Load 8 contiguous elements as bf16x8, converting if the source is fp32.
__device__ inline bf16x8 ld8(const __bf16* p) { return *(const bf16x8*)p; }
__device__ inline bf16x8 ld8(const float* p) {
  float4 a = *(const float4*)p;
  float4 b = *(const float4*)(p + 4);
  bf16x8 r;
  r[0] = (__bf16)a.x; r[1] = (__bf16)a.y; r[2] = (__bf16)a.z; r[3] = (__bf16)a.w;
  r[4] = (__bf16)b.x; r[5] = (__bf16)b.y; r[6] = (__bf16)b.z; r[7] = (__bf16)b.w;
  return r;
}

// ---------------------------------------------------------------------------
// GEMM: out[M,N] = A[M,K] @ B[N,K]^T.  A,B may be fp32 (converted to bf16 in
// staging) or bf16. 128x128 tile, BK=32, 256 threads / 4 waves.
// B rows sourced from up to 3 segments (Wq|Wk|Wv concatenation along N).
// ---------------------------------------------------------------------------
template <typename TA, typename TB>
__global__ __launch_bounds__(256) void gemm_bt_kernel(
    const TA* __restrict__ A, int K, int N,
    const TB* __restrict__ B0, int e0,
    const TB* __restrict__ B1, int e1,
    const TB* __restrict__ B2,
    float* __restrict__ outF)
{
  __shared__ __bf16 la[128 * 40];   // pad 32->40: 2-way LDS aliasing only
  __shared__ __bf16 lb[128 * 40];
  const int m0 = blockIdx.y * 128;
  const int n0 = blockIdx.x * 128;
  const TB* Bs; int nrel;
  if (n0 < e0)      { Bs = B0; nrel = n0; }
  else if (n0 < e1) { Bs = B1; nrel = n0 - e0; }
  else              { Bs = B2; nrel = n0 - e1; }
  const int tid = threadIdx.x;
  const int arow = tid >> 2, acol = (tid & 3) * 8;
  const TA* ap = A  + (size_t)(m0   + arow) * K + acol;
  const TB* bp = Bs + (size_t)(nrel + arow) * K + acol;
  const int w = tid >> 6, lane = tid & 63, lq = lane >> 4, ln = lane & 15;
  const int wm = (w >> 1) * 64, wn = (w & 1) * 64;
  f32x4 acc[4][4] = {};
  for (int k0 = 0; k0 < K; k0 += 32) {
    bf16x8 a0 = ld8(ap + k0);
    bf16x8 a1 = ld8(ap + (size_t)64 * K + k0);
    bf16x8 b0 = ld8(bp + k0);
    bf16x8 b1 = ld8(bp + (size_t)64 * K + k0);
    __syncthreads();
    *(bf16x8*)(la + arow * 40 + acol) = a0;
    *(bf16x8*)(la + (arow + 64) * 40 + acol) = a1;
    *(bf16x8*)(lb + arow * 40 + acol) = b0;
    *(bf16x8*)(lb + (arow + 64) * 40 + acol) = b1;
    __syncthreads();
    bf16x8 af[4], bfr[4];
#pragma unroll
    for (int i = 0; i < 4; ++i)
      af[i] = *(const bf16x8*)(la + (wm + i * 16 + ln) * 40 + lq * 8);
#pragma unroll
    for (int j = 0; j < 4; ++j)
      bfr[j] = *(const bf16x8*)(lb + (wn + j * 16 + ln) * 40 + lq * 8);
#pragma unroll
    for (int i = 0; i < 4; ++i)
#pragma unroll
      for (int j = 0; j < 4; ++j)
        acc[i][j] = MFMA_BF16(af[i], bfr[j], acc[i][j], 0, 0, 0);
  }
#pragma unroll
  for (int i = 0; i < 4; ++i)
#pragma unroll
    for (int j = 0; j < 4; ++j)
#pragma unroll
      for (int r = 0; r < 4; ++r) {
        int row = m0 + wm + i * 16 + lq * 4 + r;
        int col = n0 + wn + j * 16 + ln;
        outF[(size_t)row * N + col] = acc[i][j][r];
      }
}

// ---------------------------------------------------------------------------
// Gates: per (t,h): lam = elu(x.wl)+1; logit = (x.fw^T + b)*lam;
//        log_f = log_sigmoid(logit)/(lam+1e-3).  All inputs fp32.
// ---------------------------------------------------------------------------
__global__ __launch_bounds__(256) void gates_kernel(
    const float* __restrict__ x, const float* __restrict__ fw,
    const float* __restrict__ fb, const float* __restrict__ wl,
    float* __restrict__ logf)
{
  const int t = blockIdx.x;
  const int tid = threadIdx.x, w = tid >> 6, lane = tid & 63;
  float xv[16];
#pragma unroll
  for (int i = 0; i < 16; ++i)
    xv[i] = x[(size_t)t * C_ + i * 64 + lane];
#pragma unroll
  for (int u = 0; u < 4; ++u) {
    int h = w * 4 + u;
    float s1 = 0.f, s2 = 0.f;
#pragma unroll
    for (int i = 0; i < 16; ++i) {
      int cidx = i * 64 + lane;
      s1 += xv[i] * wl[(size_t)cidx * H_ + h];
      s2 += xv[i] * fw[(size_t)h * C_ + cidx];
    }
    for (int m = 32; m; m >>= 1) {
      s1 += __shfl_xor(s1, m);
      s2 += __shfl_xor(s2, m);
    }
    if (lane == 0) {
      float lam = (s1 > 0.f ? s1 : expm1f(s1)) + 1.0f;
      float logit = (s2 + fb[h]) * lam;
      float ls = (logit >= 0.f) ? -log1pf(expf(-logit))
                                : (logit - log1pf(expf(logit)));
      logf[(size_t)h * T_ + t] = ls / (lam + 1e-3f);
    }
  }
}

// ---------------------------------------------------------------------------
// Cumsum along T per head: one wave per head.
// ---------------------------------------------------------------------------
__global__ __launch_bounds__(64) void cumsum_kernel(
    const float* __restrict__ logf, float* __restrict__ csum)
{
  const int h = blockIdx.x;
  const int lane = threadIdx.x;
  float carry = 0.f;
  for (int ch = 0; ch < T_ / 64; ++ch) {
    float v = logf[(size_t)h * T_ + ch * 64 + lane];
#pragma unroll
    for (int d = 1; d < 64; d <<= 1) {
      float tv = __shfl_up(v, d);
      if (lane >= d) v += tv;
    }
    v += carry;
    csum[(size_t)h * T_ + ch * 64 + lane] = v;
    carry = __shfl(v, 63);
  }
}

// ---------------------------------------------------------------------------
// RMSNorm(q over C, k over KV) + RoPE + split into per-head bf16 Q/K/V.
// Block per t, 256 threads. Accurate sincosf (v_sin_f32 domain is limited).
// ---------------------------------------------------------------------------
__global__ __launch_bounds__(256) void normrope_kernel(
    const float* __restrict__ qkv, const float* __restrict__ qw,
    const float* __restrict__ kw, __bf16* __restrict__ qh,
    __bf16* __restrict__ kh, __bf16* __restrict__ vh)
{
  const int t = blockIdx.x, tid = threadIdx.x;
  __shared__ float qn[1024];
  __shared__ float kn[256];
  __shared__ float red[16];
  const float* row = qkv + (size_t)t * 1536;
  float4 q4 = *(const float4*)(row + tid * 4);
  float kvl = row[1024 + tid];
  float vvl = row[1280 + tid];
  float ssq = q4.x * q4.x + q4.y * q4.y + q4.z * q4.z + q4.w * q4.w;
  float ssk = kvl * kvl;
  const int lane = tid & 63, w = tid >> 6;
  for (int m = 32; m; m >>= 1) {
    ssq += __shfl_xor(ssq, m);
    ssk += __shfl_xor(ssk, m);
  }
  if (lane == 0) { red[w] = ssq; red[8 + w] = ssk; }
  __syncthreads();
  float sq = red[0] + red[1] + red[2] + red[3];
  float sk = red[8] + red[9] + red[10] + red[11];
  float rq = rsqrtf(sq * (1.0f / 1024.f) + 1e-6f);
  float rk = rsqrtf(sk * (1.0f / 256.f) + 1e-6f);
  qn[tid * 4 + 0] = q4.x * rq * qw[tid * 4 + 0];
  qn[tid * 4 + 1] = q4.y * rq * qw[tid * 4 + 1];
  qn[tid * 4 + 2] = q4.z * rq * qw[tid * 4 + 2];
  qn[tid * 4 + 3] = q4.w * rq * qw[tid * 4 + 3];
  kn[tid] = kvl * rk * kw[tid];
  __syncthreads();
  // log2(10000)/32 = 0.415241011864...
#pragma unroll
  for (int u = 0; u < 4; ++u) {
    int cidx = tid * 4 + u;
    int hh = cidx >> 6, d = cidx & 63, i = d & 31;
    float fr = (float)t * exp2f((float)i * -0.41524101186404527f);
    float sn, cs;
    sincosf(fr, &sn, &cs);
    float val = (d < 32) ? (qn[cidx] * cs - qn[cidx + 32] * sn)
                         : (qn[cidx] * cs + qn[cidx - 32] * sn);
    qh[(size_t)hh * T_ * D_ + (size_t)t * D_ + d] = (__bf16)val;
  }
  {
    int d = tid & 63, kvhh = tid >> 6, i = d & 31;
    float fr = (float)t * exp2f((float)i * -0.41524101186404527f);
    float sn, cs;
    sincosf(fr, &sn, &cs);
    float kval = (d < 32) ? (kn[tid] * cs - kn[tid + 32] * sn)
                          : (kn[tid] * cs + kn[tid - 32] * sn);
    kh[(size_t)kvhh * T_ * D_ + (size_t)t * D_ + d] = (__bf16)kval;
    vh[(size_t)kvhh * T_ * D_ + (size_t)t * D_ + d] = (__bf16)vvl;
  }
}

// ---------------------------------------------------------------------------
// Transpose V: [KVH][T][D] -> [KVH][D][T] (64x64 LDS tiles)
// ---------------------------------------------------------------------------
__global__ __launch_bounds__(256) void vtrans_kernel(
    const __bf16* __restrict__ vh, __bf16* __restrict__ vt)
{
  const int tb = blockIdx.x, kvh = blockIdx.y;
  __shared__ __bf16 tile[64][72];
  const int tid = threadIdx.x;
  const int r = tid >> 2, cb = (tid & 3) * 16;
  const __bf16* src = vh + (size_t)kvh * T_ * D_ + (size_t)(tb * 64 + r) * D_ + cb;
  bf16x8 v0 = *(const bf16x8*)(src);
  bf16x8 v1 = *(const bf16x8*)(src + 8);
  *(bf16x8*)(&tile[r][cb]) = v0;
  *(bf16x8*)(&tile[r][cb + 8]) = v1;
  __syncthreads();
  bf16x8 o0, o1;
#pragma unroll
  for (int j = 0; j < 8; ++j) o0[j] = tile[cb + j][r];
#pragma unroll
  for (int j = 0; j < 8; ++j) o1[j] = tile[cb + 8 + j][r];
  __bf16* dst = vt + (size_t)kvh * D_ * T_ + (size_t)r * T_ + tb * 64 + cb;
  *(bf16x8*)(dst) = o0;
  *(bf16x8*)(dst + 8) = o1;
}

// ---------------------------------------------------------------------------
// Flash attention with FoX bias. Block = (head, 64-row q-block), 4 waves,
// each wave owns 16 q-rows. K/V^T tiles staged in LDS per j-tile.
// ---------------------------------------------------------------------------
__global__ __launch_bounds__(256) void attn_kernel(
    const __bf16* __restrict__ qh, const __bf16* __restrict__ kh,
    const __bf16* __restrict__ vt, const float* __restrict__ csum,
    __bf16* __restrict__ y)
{
  const int ib = blockIdx.x, h = blockIdx.y;
  const int i0 = ib * 64, kvh = h >> 2;
  __shared__ __bf16 qt[64 * 72];
  __shared__ __bf16 kt[64 * 72];
  __shared__ __bf16 vtt[64 * 72];
  __shared__ __bf16 pt[4][16 * 72];
  const int tid = threadIdx.x;
  const int w = tid >> 6, lane = tid & 63, lq = lane >> 4, ln = lane & 15;
  const int srow = tid >> 2, scol = (tid & 3) * 16;
  {
    const __bf16* src = qh + ((size_t)h * T_ + i0 + srow) * D_ + scol;
    bf16x8 v0 = *(const bf16x8*)(src);
    bf16x8 v1 = *(const bf16x8*)(src + 8);
    *(bf16x8*)(qt + srow * 72 + scol) = v0;
    *(bf16x8*)(qt + srow * 72 + scol + 8) = v1;
  }
  __syncthreads();
  bf16x8 aq0 = *(const bf16x8*)(qt + (w * 16 + ln) * 72 + lq * 8);
  bf16x8 aq1 = *(const bf16x8*)(qt + (w * 16 + ln) * 72 + 32 + lq * 8);
  float ci[4], mres[4], lres[4];
  f32x4 o[4] = {};
#pragma unroll
  for (int r = 0; r < 4; ++r) {
    ci[r] = csum[(size_t)h * T_ + i0 + w * 16 + lq * 4 + r];
    mres[r] = NEG_BIG;
    lres[r] = 0.f;
  }
  __bf16* pw = &pt[w][0];
  for (int jt = 0; jt <= ib; ++jt) {
    const int j0 = jt * 64;
    __syncthreads();
    {
      const __bf16* ksrc = kh + ((size_t)kvh * T_ + j0 + srow) * D_ + scol;
      bf16x8 k0 = *(const bf16x8*)(ksrc);
      bf16x8 k1 = *(const bf16x8*)(ksrc + 8);
      const __bf16* vsrc = vt + (size_t)kvh * D_ * T_ + (size_t)srow * T_ + j0 + scol;
      bf16x8 vv0 = *(const bf16x8*)(vsrc);
      bf16x8 vv1 = *(const bf16x8*)(vsrc + 8);
      *(bf16x8*)(kt + srow * 72 + scol) = k0;
      *(bf16x8*)(kt + srow * 72 + scol + 8) = k1;
      *(bf16x8*)(vtt + srow * 72 + scol) = vv0;
      *(bf16x8*)(vtt + srow * 72 + scol + 8) = vv1;
    }
    __syncthreads();
    f32x4 s[4];
    f32x4 zf = {0.f, 0.f, 0.f, 0.f};
#pragma unroll
    for (int jj = 0; jj < 4; ++jj) {
      bf16x8 bk0 = *(const bf16x8*)(kt + (jj * 16 + ln) * 72 + lq * 8);
      bf16x8 bk1 = *(const bf16x8*)(kt + (jj * 16 + ln) * 72 + 32 + lq * 8);
      s[jj] = MFMA_BF16(aq0, bk0, zf, 0, 0, 0);
      s[jj] = MFMA_BF16(aq1, bk1, s[jj], 0, 0, 0);
    }
    float cj[4];
#pragma unroll
    for (int jj = 0; jj < 4; ++jj)
      cj[jj] = csum[(size_t)h * T_ + j0 + jj * 16 + ln];
    float rmax[4] = {NEG_BIG, NEG_BIG, NEG_BIG, NEG_BIG};
#pragma unroll
    for (int jj = 0; jj < 4; ++jj)
#pragma unroll
      for (int r = 0; r < 4; ++r) {
        int iabs = i0 + w * 16 + lq * 4 + r;
        int jabs = j0 + jj * 16 + ln;
        float val = s[jj][r] * SCALE_ + ci[r] - cj[jj];
        val = (jabs > iabs) ? NEG_BIG : val;
        s[jj][r] = val;
        rmax[r] = fmaxf(rmax[r], val);
      }
#pragma unroll
    for (int off = 8; off; off >>= 1)
#pragma unroll
      for (int r = 0; r < 4; ++r)
        rmax[r] = fmaxf(rmax[r], __shfl_xor(rmax[r], off));
    float alpha[4];
#pragma unroll
    for (int r = 0; r < 4; ++r) {
      float mn = fmaxf(mres[r], rmax[r]);
      alpha[r] = __expf(mres[r] - mn);
      mres[r] = mn;
    }
    float rsum[4] = {0.f, 0.f, 0.f, 0.f};
#pragma unroll
    for (int jj = 0; jj < 4; ++jj)
#pragma unroll
      for (int r = 0; r < 4; ++r) {
        float p = __expf(s[jj][r] - mres[r]);
        s[jj][r] = p;
        rsum[r] += p;
      }
#pragma unroll
    for (int off = 8; off; off >>= 1)
#pragma unroll
      for (int r = 0; r < 4; ++r)
        rsum[r] += __shfl_xor(rsum[r], off);
#pragma unroll
    for (int r = 0; r < 4; ++r)
      lres[r] = lres[r] * alpha[r] + rsum[r];
#pragma unroll
    for (int dd = 0; dd < 4; ++dd)
#pragma unroll
      for (int r = 0; r < 4; ++r)
        o[dd][r] *= alpha[r];
    // P (C-layout) -> LDS -> A-layout frags. Barrier: cross-lane exchange.
#pragma unroll
    for (int jj = 0; jj < 4; ++jj)
#pragma unroll
      for (int r = 0; r < 4; ++r)
        pw[(lq * 4 + r) * 72 + jj * 16 + ln] = (__bf16)s[jj][r];
    __syncthreads();
    bf16x8 pa0 = *(const bf16x8*)(pw + ln * 72 + lq * 8);
    bf16x8 pa1 = *(const bf16x8*)(pw + ln * 72 + 32 + lq * 8);
#pragma unroll
    for (int dd = 0; dd < 4; ++dd) {
      bf16x8 bv0 = *(const bf16x8*)(vtt + (dd * 16 + ln) * 72 + lq * 8);
      bf16x8 bv1 = *(const bf16x8*)(vtt + (dd * 16 + ln) * 72 + 32 + lq * 8);
      o[dd] = MFMA_BF16(pa0, bv0, o[dd], 0, 0, 0);
      o[dd] = MFMA_BF16(pa1, bv1, o[dd], 0, 0, 0);
    }
  }
#pragma unroll
  for (int dd = 0; dd < 4; ++dd)
#pragma unroll
    for (int r = 0; r < 4; ++r) {
      int iabs = i0 + w * 16 + lq * 4 + r;
      int col = h * 64 + dd * 16 + ln;
      y[(size_t)iabs * C_ + col] = (__bf16)(o[dd][r] / lres[r]);
    }
}

// ---------------------------------------------------------------------------
extern "C" void kernel_launch(void* const* d_in, const int* in_sizes, int n_in,
                              void* d_out, int out_size, void* d_ws, size_t ws_size,
                              hipStream_t stream) {
  const float* x   = (const float*)d_in[0];
  const float* Wq  = (const float*)d_in[1];
  const float* Wk  = (const float*)d_in[2];
  const float* Wv  = (const float*)d_in[3];
  const float* Wo  = (const float*)d_in[4];
  const float* qnw = (const float*)d_in[5];
  const float* knw = (const float*)d_in[6];
  const float* fgw = (const float*)d_in[7];
  const float* fgb = (const float*)d_in[8];
  const float* wl  = (const float*)d_in[9];

  char* ws = (char*)d_ws;
  size_t off = 0;
  float*  qkv  = (float*)(ws + off);  off += (size_t)T_ * 1536 * 4;      // 12.6 MB
  float*  logf = (float*)(ws + off);  off += (size_t)H_ * T_ * 4;        // 128 KB
  float*  csum = (float*)(ws + off);  off += (size_t)H_ * T_ * 4;        // 128 KB
  __bf16* qh   = (__bf16*)(ws + off); off += (size_t)H_ * T_ * D_ * 2;   // 4 MB
  __bf16* kh   = (__bf16*)(ws + off); off += (size_t)KVH_ * T_ * D_ * 2; // 1 MB
  __bf16* vh   = (__bf16*)(ws + off); off += (size_t)KVH_ * T_ * D_ * 2; // 1 MB
  __bf16* vt   = (__bf16*)(ws + off); off += (size_t)KVH_ * T_ * D_ * 2; // 1 MB
  __bf16* y    = (__bf16*)(ws + off); off += (size_t)T_ * C_ * 2;        // 4 MB

  // 1) QKV projection: fp32 in, bf16 MFMA, fp32 out [2048,1536]
  gemm_bt_kernel<float, float><<<dim3(12, 16), 256, 0, stream>>>(
      x, 1024, 1536, Wq, 1024, Wk, 1280, Wv, qkv);
  // 2) Forgetting-gate logits -> log_f [H][T]
  gates_kernel<<<T_, 256, 0, stream>>>(x, fgw, fgb, wl, logf);
  // 3) cumsum -> c [H][T]
  cumsum_kernel<<<H_, 64, 0, stream>>>(logf, csum);
  // 4) RMSNorm + RoPE -> per-head bf16 q/k/v
  normrope_kernel<<<T_, 256, 0, stream>>>(qkv, qnw, knw, qh, kh, vh);
  // 5) V transpose for PV MFMA B-operand
  vtrans_kernel<<<dim3(T_ / 64, KVH_), 256, 0, stream>>>(vh, vt);
  // 6) flash attention with FoX bias -> y [T][C] bf16
  attn_kernel<<<dim3(T_ / 64, H_), 256, 0, stream>>>(qh, kh, vt, csum, y);
  // 7) output projection -> d_out fp32
  gemm_bt_kernel<__bf16, float><<<dim3(8, 16), 256, 0, stream>>>(
      y, 1024, 1024, Wo, 1024, Wo, 1024, Wo, (float*)d_out);
}

// Round 5
// 204.286 us; speedup vs baseline: 1.4842x; 1.4842x over previous
//
#include <hip/hip_runtime.h>

typedef __bf16 bf16x8 __attribute__((ext_vector_type(8)));
typedef float f32x4 __attribute__((ext_vector_type(4)));

#define MFMA_BF16 __builtin_amdgcn_mfma_f32_16x16x32_bf16

static constexpr int T_ = 2048;
static constexpr int C_ = 1024;
static constexpr int H_ = 16;
static constexpr int KVH_ = 4;
static constexpr int D_ = 64;
static constexpr float SCALE_ = 0.125f;   // 1/sqrt(64)
// Fixed softmax shift: scores = qk*SCALE + (ci-cj) with ci-cj<=0 and
// |qk|*SCALE <= |q||k|/8 = 8 (rmsnorm'd) -> row max in [-8, 8]. Shift by 10:
// exp args <= -2 (no overflow); row max term >= exp(-18) (no 0/0).
static constexpr float MSHIFT_ = 10.0f;

// ---------------------------------------------------------------------------
// fp32 -> bf16 conversion of x, Wq, Wk, Wv, Wo + fp32 transpose of wl.
// ---------------------------------------------------------------------------
__device__ inline void cvt8(__bf16* dst, const float* src) {
  float4 a = *(const float4*)src;
  float4 b = *(const float4*)(src + 4);
  bf16x8 r;
  r[0] = (__bf16)a.x; r[1] = (__bf16)a.y; r[2] = (__bf16)a.z; r[3] = (__bf16)a.w;
  r[4] = (__bf16)b.x; r[5] = (__bf16)b.y; r[6] = (__bf16)b.z; r[7] = (__bf16)b.w;
  *(bf16x8*)dst = r;
}

__global__ __launch_bounds__(256) void cvt_kernel(
    const float* __restrict__ x,  const float* __restrict__ wq,
    const float* __restrict__ wk, const float* __restrict__ wv,
    const float* __restrict__ wo, const float* __restrict__ wl,
    __bf16* __restrict__ xb,  __bf16* __restrict__ wqb,
    __bf16* __restrict__ wkb, __bf16* __restrict__ wvb,
    __bf16* __restrict__ wob, float* __restrict__ wlT)
{
  size_t i8 = ((size_t)blockIdx.x * 256 + threadIdx.x) * 8;
  // segment boundaries (elements): x 2097152 | Wq 1048576 | Wk 262144 |
  // Wv 262144 | Wo 1048576 | wlT 16384
  if (i8 < 2097152)       cvt8(xb  + i8,            x  + i8);
  else if (i8 < 3145728)  cvt8(wqb + (i8-2097152),  wq + (i8-2097152));
  else if (i8 < 3407872)  cvt8(wkb + (i8-3145728),  wk + (i8-3145728));
  else if (i8 < 3670016)  cvt8(wvb + (i8-3407872),  wv + (i8-3407872));
  else if (i8 < 4718592)  cvt8(wob + (i8-3670016),  wo + (i8-3670016));
  else {
    size_t r = i8 - 4718592;
    if (r < 16384) {
#pragma unroll
      for (int j = 0; j < 8; ++j) {
        size_t idx = r + j;              // idx = h*1024 + c
        size_t hh = idx >> 10, c = idx & 1023;
        wlT[idx] = wl[c * 16 + hh];
      }
    }
  }
}

// ---------------------------------------------------------------------------
// GEMM: out[M,N] = A[M,K] @ B[N,K]^T, all bf16, fp32 out.
// BM x 128 tile, BK=32, 256 threads / 4 waves (each (BM/2) x 64).
// ---------------------------------------------------------------------------
template <int BM>
__global__ __launch_bounds__(256) void gemm_bt_kernel(
    const __bf16* __restrict__ A, int K, int N,
    const __bf16* __restrict__ B0, int e0,
    const __bf16* __restrict__ B1, int e1,
    const __bf16* __restrict__ B2,
    float* __restrict__ outF)
{
  __shared__ __bf16 la[BM * 40];
  __shared__ __bf16 lb[128 * 40];
  const int m0 = blockIdx.y * BM;
  const int n0 = blockIdx.x * 128;
  const __bf16* Bs; int nrel;
  if (n0 < e0)      { Bs = B0; nrel = n0; }
  else if (n0 < e1) { Bs = B1; nrel = n0 - e0; }
  else              { Bs = B2; nrel = n0 - e1; }
  const int tid = threadIdx.x;
  const int arow = tid >> 2, acol = (tid & 3) * 8;
  const __bf16* ap = A  + (size_t)(m0   + arow) * K + acol;
  const __bf16* bp = Bs + (size_t)(nrel + arow) * K + acol;
  const int w = tid >> 6, lane = tid & 63, lq = lane >> 4, ln = lane & 15;
  const int wm = (w >> 1) * (BM / 2), wn = (w & 1) * 64;
  constexpr int FM = BM / 32;
  f32x4 acc[FM][4] = {};
  for (int k0 = 0; k0 < K; k0 += 32) {
    bf16x8 a0 = *(const bf16x8*)(ap + k0);
    bf16x8 a1{};
    if (BM == 128) a1 = *(const bf16x8*)(ap + (size_t)64 * K + k0);
    bf16x8 b0 = *(const bf16x8*)(bp + k0);
    bf16x8 b1 = *(const bf16x8*)(bp + (size_t)64 * K + k0);
    __syncthreads();
    *(bf16x8*)(la + arow * 40 + acol) = a0;
    if (BM == 128) *(bf16x8*)(la + (arow + 64) * 40 + acol) = a1;
    *(bf16x8*)(lb + arow * 40 + acol) = b0;
    *(bf16x8*)(lb + (arow + 64) * 40 + acol) = b1;
    __syncthreads();
    bf16x8 af[FM], bfr[4];
#pragma unroll
    for (int i = 0; i < FM; ++i)
      af[i] = *(const bf16x8*)(la + (wm + i * 16 + ln) * 40 + lq * 8);
#pragma unroll
    for (int j = 0; j < 4; ++j)
      bfr[j] = *(const bf16x8*)(lb + (wn + j * 16 + ln) * 40 + lq * 8);
#pragma unroll
    for (int i = 0; i < FM; ++i)
#pragma unroll
      for (int j = 0; j < 4; ++j)
        acc[i][j] = MFMA_BF16(af[i], bfr[j], acc[i][j], 0, 0, 0);
  }
#pragma unroll
  for (int i = 0; i < FM; ++i)
#pragma unroll
    for (int j = 0; j < 4; ++j)
#pragma unroll
      for (int r = 0; r < 4; ++r) {
        int row = m0 + wm + i * 16 + lq * 4 + r;
        int col = n0 + wn + j * 16 + ln;
        outF[(size_t)row * N + col] = acc[i][j][r];
      }
}

// ---------------------------------------------------------------------------
// Gates: per (t,h): lam = elu(x.wl)+1; logit = (x.fw^T+b)*lam;
//        log_f = log_sigmoid(logit)/(lam+1e-3). wlT is [H][C] (coalesced).
// ---------------------------------------------------------------------------
__global__ __launch_bounds__(256) void gates_kernel(
    const float* __restrict__ x, const float* __restrict__ fw,
    const float* __restrict__ fb, const float* __restrict__ wlT,
    float* __restrict__ logf)
{
  const int t = blockIdx.x;
  const int tid = threadIdx.x, w = tid >> 6, lane = tid & 63;
  float xv[16];
#pragma unroll
  for (int i = 0; i < 16; ++i)
    xv[i] = x[(size_t)t * C_ + i * 64 + lane];
#pragma unroll
  for (int u = 0; u < 4; ++u) {
    int h = w * 4 + u;
    float s1 = 0.f, s2 = 0.f;
#pragma unroll
    for (int i = 0; i < 16; ++i) {
      int cidx = i * 64 + lane;
      s1 += xv[i] * wlT[(size_t)h * C_ + cidx];
      s2 += xv[i] * fw[(size_t)h * C_ + cidx];
    }
    for (int m = 32; m; m >>= 1) {
      s1 += __shfl_xor(s1, m);
      s2 += __shfl_xor(s2, m);
    }
    if (lane == 0) {
      float lam = (s1 > 0.f ? s1 : expm1f(s1)) + 1.0f;
      float logit = (s2 + fb[h]) * lam;
      float ls = (logit >= 0.f) ? -log1pf(expf(-logit))
                                : (logit - log1pf(expf(logit)));
      logf[(size_t)h * T_ + t] = ls / (lam + 1e-3f);
    }
  }
}

// ---------------------------------------------------------------------------
// Cumsum along T per head: one wave per head.
// ---------------------------------------------------------------------------
__global__ __launch_bounds__(64) void cumsum_kernel(
    const float* __restrict__ logf, float* __restrict__ csum)
{
  const int h = blockIdx.x;
  const int lane = threadIdx.x;
  float carry = 0.f;
  for (int ch = 0; ch < T_ / 64; ++ch) {
    float v = logf[(size_t)h * T_ + ch * 64 + lane];
#pragma unroll
    for (int d = 1; d < 64; d <<= 1) {
      float tv = __shfl_up(v, d);
      if (lane >= d) v += tv;
    }
    v += carry;
    csum[(size_t)h * T_ + ch * 64 + lane] = v;
    carry = __shfl(v, 63);
  }
}

// ---------------------------------------------------------------------------
// RMSNorm + RoPE + head split. Rope table computed once per block (32 accurate
// sincosf calls instead of 1280; v_sin_f32 domain too small for t*invfreq).
// ---------------------------------------------------------------------------
__global__ __launch_bounds__(256) void normrope_kernel(
    const float* __restrict__ qkv, const float* __restrict__ qw,
    const float* __restrict__ kw, __bf16* __restrict__ qh,
    __bf16* __restrict__ kh, __bf16* __restrict__ vh)
{
  const int t = blockIdx.x, tid = threadIdx.x;
  __shared__ float qn[1024];
  __shared__ float kn[256];
  __shared__ float red[16];
  __shared__ float rc[32], rs[32];
  if (tid < 32) {
    float fr = (float)t * exp2f((float)tid * -0.41524101186404527f);
    float sn, cs;
    sincosf(fr, &sn, &cs);
    rc[tid] = cs; rs[tid] = sn;
  }
  const float* row = qkv + (size_t)t * 1536;
  float4 q4 = *(const float4*)(row + tid * 4);
  float kvl = row[1024 + tid];
  float vvl = row[1280 + tid];
  float ssq = q4.x * q4.x + q4.y * q4.y + q4.z * q4.z + q4.w * q4.w;
  float ssk = kvl * kvl;
  const int lane = tid & 63, w = tid >> 6;
  for (int m = 32; m; m >>= 1) {
    ssq += __shfl_xor(ssq, m);
    ssk += __shfl_xor(ssk, m);
  }
  if (lane == 0) { red[w] = ssq; red[8 + w] = ssk; }
  __syncthreads();
  float sq = red[0] + red[1] + red[2] + red[3];
  float sk = red[8] + red[9] + red[10] + red[11];
  float rq = rsqrtf(sq * (1.0f / 1024.f) + 1e-6f);
  float rk = rsqrtf(sk * (1.0f / 256.f) + 1e-6f);
  qn[tid * 4 + 0] = q4.x * rq * qw[tid * 4 + 0];
  qn[tid * 4 + 1] = q4.y * rq * qw[tid * 4 + 1];
  qn[tid * 4 + 2] = q4.z * rq * qw[tid * 4 + 2];
  qn[tid * 4 + 3] = q4.w * rq * qw[tid * 4 + 3];
  kn[tid] = kvl * rk * kw[tid];
  __syncthreads();
#pragma unroll
  for (int u = 0; u < 4; ++u) {
    int cidx = tid * 4 + u;
    int hh = cidx >> 6, d = cidx & 63, i = d & 31;
    float cs = rc[i], sn = rs[i];
    float val = (d < 32) ? (qn[cidx] * cs - qn[cidx + 32] * sn)
                         : (qn[cidx] * cs + qn[cidx - 32] * sn);
    qh[(size_t)hh * T_ * D_ + (size_t)t * D_ + d] = (__bf16)val;
  }
  {
    int d = tid & 63, kvhh = tid >> 6, i = d & 31;
    float cs = rc[i], sn = rs[i];
    float kval = (d < 32) ? (kn[tid] * cs - kn[tid + 32] * sn)
                          : (kn[tid] * cs + kn[tid - 32] * sn);
    kh[(size_t)kvhh * T_ * D_ + (size_t)t * D_ + d] = (__bf16)kval;
    vh[(size_t)kvhh * T_ * D_ + (size_t)t * D_ + d] = (__bf16)vvl;
  }
}

// ---------------------------------------------------------------------------
// Transpose V: [KVH][T][D] -> [KVH][D][T]
// ---------------------------------------------------------------------------
__global__ __launch_bounds__(256) void vtrans_kernel(
    const __bf16* __restrict__ vh, __bf16* __restrict__ vt)
{
  const int tb = blockIdx.x, kvh = blockIdx.y;
  __shared__ __bf16 tile[64][72];
  const int tid = threadIdx.x;
  const int r = tid >> 2, cb = (tid & 3) * 16;
  const __bf16* src = vh + (size_t)kvh * T_ * D_ + (size_t)(tb * 64 + r) * D_ + cb;
  bf16x8 v0 = *(const bf16x8*)(src);
  bf16x8 v1 = *(const bf16x8*)(src + 8);
  *(bf16x8*)(&tile[r][cb]) = v0;
  *(bf16x8*)(&tile[r][cb + 8]) = v1;
  __syncthreads();
  bf16x8 o0, o1;
#pragma unroll
  for (int j = 0; j < 8; ++j) o0[j] = tile[cb + j][r];
#pragma unroll
  for (int j = 0; j < 8; ++j) o1[j] = tile[cb + 8 + j][r];
  __bf16* dst = vt + (size_t)kvh * D_ * T_ + (size_t)r * T_ + tb * 64 + cb;
  *(bf16x8*)(dst) = o0;
  *(bf16x8*)(dst + 8) = o1;
}

// ---------------------------------------------------------------------------
// Flash attention v2: constant-shift softmax (no online max), ones-MFMA row
// sums, diagonal-only masking, Q frags from global, register K/V prefetch.
// Block = (64 q-rows, head); 4 waves x 16 rows.
// ---------------------------------------------------------------------------
__global__ __launch_bounds__(256) void attn_kernel(
    const __bf16* __restrict__ qh, const __bf16* __restrict__ kh,
    const __bf16* __restrict__ vt, const float* __restrict__ csum,
    __bf16* __restrict__ y)
{
  const int ib = blockIdx.x, h = blockIdx.y;
  const int i0 = ib * 64, kvh = h >> 2;
  __shared__ __bf16 kt[64 * 72];
  __shared__ __bf16 vtt[64 * 72];
  __shared__ __bf16 pt[4][16 * 72];
  const int tid = threadIdx.x;
  const int w = tid >> 6, lane = tid & 63, lq = lane >> 4, ln = lane & 15;
  const int srow = tid >> 2, scol = (tid & 3) * 16;
  const __bf16* kbase = kh + (size_t)kvh * T_ * D_;   // [t][d]
  const __bf16* vbase = vt + (size_t)kvh * D_ * T_;   // [d][t]
  // Q A-frags direct from global
  const __bf16* qp = qh + ((size_t)h * T_ + i0 + w * 16 + ln) * D_;
  bf16x8 aq0 = *(const bf16x8*)(qp + lq * 8);
  bf16x8 aq1 = *(const bf16x8*)(qp + 32 + lq * 8);
  float ci[4];
#pragma unroll
  for (int r = 0; r < 4; ++r)
    ci[r] = csum[(size_t)h * T_ + i0 + w * 16 + lq * 4 + r];
  f32x4 o[4] = {};
  f32x4 ls = {0.f, 0.f, 0.f, 0.f};
  bf16x8 ones;
#pragma unroll
  for (int j = 0; j < 8; ++j) ones[j] = (__bf16)1.0f;
  __bf16* pw = &pt[w][0];

  // stage tile 0
  bf16x8 kr0 = *(const bf16x8*)(kbase + (size_t)srow * D_ + scol);
  bf16x8 kr1 = *(const bf16x8*)(kbase + (size_t)srow * D_ + scol + 8);
  bf16x8 vr0 = *(const bf16x8*)(vbase + (size_t)srow * T_ + scol);
  bf16x8 vr1 = *(const bf16x8*)(vbase + (size_t)srow * T_ + scol + 8);
  *(bf16x8*)(kt + srow * 72 + scol) = kr0;
  *(bf16x8*)(kt + srow * 72 + scol + 8) = kr1;
  *(bf16x8*)(vtt + srow * 72 + scol) = vr0;
  *(bf16x8*)(vtt + srow * 72 + scol + 8) = vr1;
  __syncthreads();

  auto tilebody = [&](int j0, bool diag) {
    f32x4 s[4];
    const f32x4 zf = {0.f, 0.f, 0.f, 0.f};
#pragma unroll
    for (int jj = 0; jj < 4; ++jj) {
      bf16x8 bk0 = *(const bf16x8*)(kt + (jj * 16 + ln) * 72 + lq * 8);
      bf16x8 bk1 = *(const bf16x8*)(kt + (jj * 16 + ln) * 72 + 32 + lq * 8);
      s[jj] = MFMA_BF16(aq0, bk0, zf, 0, 0, 0);
      s[jj] = MFMA_BF16(aq1, bk1, s[jj], 0, 0, 0);
    }
    float cj[4];
#pragma unroll
    for (int jj = 0; jj < 4; ++jj)
      cj[jj] = csum[(size_t)h * T_ + j0 + jj * 16 + ln];
#pragma unroll
    for (int jj = 0; jj < 4; ++jj)
#pragma unroll
      for (int r = 0; r < 4; ++r) {
        float arg = fmaf(s[jj][r], SCALE_, ci[r] - cj[jj] - MSHIFT_);
        float p = __expf(arg);
        if (diag && (jj * 16 + ln > w * 16 + lq * 4 + r)) p = 0.f;
        pw[(lq * 4 + r) * 72 + jj * 16 + ln] = (__bf16)p;
      }
    // wave-local exchange: ds ops in-order per wave; fence compiler + lgkm
    asm volatile("s_waitcnt lgkmcnt(0)" ::: "memory");
    bf16x8 pa0 = *(const bf16x8*)(pw + ln * 72 + lq * 8);
    bf16x8 pa1 = *(const bf16x8*)(pw + ln * 72 + 32 + lq * 8);
    ls = MFMA_BF16(pa0, ones, ls, 0, 0, 0);
    ls = MFMA_BF16(pa1, ones, ls, 0, 0, 0);
#pragma unroll
    for (int dd = 0; dd < 4; ++dd) {
      bf16x8 bv0 = *(const bf16x8*)(vtt + (dd * 16 + ln) * 72 + lq * 8);
      bf16x8 bv1 = *(const bf16x8*)(vtt + (dd * 16 + ln) * 72 + 32 + lq * 8);
      o[dd] = MFMA_BF16(pa0, bv0, o[dd], 0, 0, 0);
      o[dd] = MFMA_BF16(pa1, bv1, o[dd], 0, 0, 0);
    }
  };

  for (int jt = 0; jt < ib; ++jt) {
    const int j0n = (jt + 1) * 64;
    // prefetch next K/V tile (overlaps compute below)
    kr0 = *(const bf16x8*)(kbase + (size_t)(j0n + srow) * D_ + scol);
    kr1 = *(const bf16x8*)(kbase + (size_t)(j0n + srow) * D_ + scol + 8);
    vr0 = *(const bf16x8*)(vbase + (size_t)srow * T_ + j0n + scol);
    vr1 = *(const bf16x8*)(vbase + (size_t)srow * T_ + j0n + scol + 8);
    tilebody(jt * 64, false);
    __syncthreads();   // all waves done reading kt/vtt
    *(bf16x8*)(kt + srow * 72 + scol) = kr0;
    *(bf16x8*)(kt + srow * 72 + scol + 8) = kr1;
    *(bf16x8*)(vtt + srow * 72 + scol) = vr0;
    *(bf16x8*)(vtt + srow * 72 + scol + 8) = vr1;
    __syncthreads();   // new tile visible
  }
  tilebody(i0, true);  // diagonal tile (masked)

#pragma unroll
  for (int dd = 0; dd < 4; ++dd)
#pragma unroll
    for (int r = 0; r < 4; ++r) {
      int iabs = i0 + w * 16 + lq * 4 + r;
      int col = h * 64 + dd * 16 + ln;
      y[(size_t)iabs * C_ + col] = (__bf16)(o[dd][r] / ls[r]);
    }
}

// ---------------------------------------------------------------------------
extern "C" void kernel_launch(void* const* d_in, const int* in_sizes, int n_in,
                              void* d_out, int out_size, void* d_ws, size_t ws_size,
                              hipStream_t stream) {
  const float* x   = (const float*)d_in[0];
  const float* Wq  = (const float*)d_in[1];
  const float* Wk  = (const float*)d_in[2];
  const float* Wv  = (const float*)d_in[3];
  const float* Wo  = (const float*)d_in[4];
  const float* qnw = (const float*)d_in[5];
  const float* knw = (const float*)d_in[6];
  const float* fgw = (const float*)d_in[7];
  const float* fgb = (const float*)d_in[8];
  const float* wl  = (const float*)d_in[9];

  char* ws = (char*)d_ws;
  size_t off = 0;
  float*  qkv  = (float*)(ws + off);  off += (size_t)T_ * 1536 * 4;       // 12.6 MB
  float*  logf = (float*)(ws + off);  off += (size_t)H_ * T_ * 4;
  float*  csum = (float*)(ws + off);  off += (size_t)H_ * T_ * 4;
  __bf16* qh   = (__bf16*)(ws + off); off += (size_t)H_ * T_ * D_ * 2;    // 4 MB
  __bf16* kh   = (__bf16*)(ws + off); off += (size_t)KVH_ * T_ * D_ * 2;
  __bf16* vh   = (__bf16*)(ws + off); off += (size_t)KVH_ * T_ * D_ * 2;
  __bf16* vt   = (__bf16*)(ws + off); off += (size_t)KVH_ * T_ * D_ * 2;
  __bf16* y    = (__bf16*)(ws + off); off += (size_t)T_ * C_ * 2;         // 4 MB
  __bf16* xb   = (__bf16*)(ws + off); off += (size_t)T_ * C_ * 2;         // 4 MB
  __bf16* wqb  = (__bf16*)(ws + off); off += (size_t)C_ * C_ * 2;         // 2 MB
  __bf16* wkb  = (__bf16*)(ws + off); off += (size_t)256 * C_ * 2;
  __bf16* wvb  = (__bf16*)(ws + off); off += (size_t)256 * C_ * 2;
  __bf16* wob  = (__bf16*)(ws + off); off += (size_t)C_ * C_ * 2;         // 2 MB
  float*  wlT  = (float*)(ws + off);  off += (size_t)H_ * C_ * 4;         // 64 KB

  // 0) fp32 -> bf16 conversions (+ wl transpose)
  cvt_kernel<<<2312, 256, 0, stream>>>(x, Wq, Wk, Wv, Wo, wl,
                                       xb, wqb, wkb, wvb, wob, wlT);
  // 1) QKV projection (bf16): [2048,1024] @ [1536,1024]^T -> fp32
  gemm_bt_kernel<64><<<dim3(12, 32), 256, 0, stream>>>(
      xb, 1024, 1536, wqb, 1024, wkb, 1280, wvb, qkv);
  // 2) gate logits -> log_f
  gates_kernel<<<T_, 256, 0, stream>>>(x, fgw, fgb, wlT, logf);
  // 3) cumsum
  cumsum_kernel<<<H_, 64, 0, stream>>>(logf, csum);
  // 4) RMSNorm + RoPE
  normrope_kernel<<<T_, 256, 0, stream>>>(qkv, qnw, knw, qh, kh, vh);
  // 5) V transpose
  vtrans_kernel<<<dim3(T_ / 64, KVH_), 256, 0, stream>>>(vh, vt);
  // 6) flash attention
  attn_kernel<<<dim3(T_ / 64, H_), 256, 0, stream>>>(qh, kh, vt, csum, y);
  // 7) output projection -> d_out fp32
  gemm_bt_kernel<64><<<dim3(8, 32), 256, 0, stream>>>(
      y, 1024, 1024, wob, 1024, wob, 1024, wob, (float*)d_out);
}